// Round 5
// baseline (31.701 us; speedup 1.0000x reference)
//
#include <hip/hip_runtime.h>

typedef _Float16 f16;
typedef __attribute__((ext_vector_type(2))) _Float16 f16x2;
typedef __attribute__((ext_vector_type(8))) _Float16 f16x8;
typedef __attribute__((ext_vector_type(4))) float f32x4;
typedef __attribute__((ext_vector_type(4))) unsigned u32x4;

constexpr int IN_F  = 4096;
constexpr int OUT_F = 11008;
constexpr int NGRP  = 32;   // 4096 / 128

// dequant one byte-holding int32 (2 nibbles) -> 2 packed f16 weights
__device__ __forceinline__ unsigned dq2(unsigned q, f16x2 sp, f16x2 zp) {
    unsigned t = (((q << 12) | q) & 0x000F000Fu) | 0x64006400u;  // (1024+lo, 1024+hi)
    f16x2 u = __builtin_bit_cast(f16x2, t);
    u = u - (f16x2){(_Float16)1024.0f, (_Float16)1024.0f};       // exact
    u = u * sp + zp;                                             // v_pk_fma_f16
    return __builtin_bit_cast(unsigned, u);
}

__device__ __forceinline__ f16x2 bcast(float v) {
    _Float16 h = (_Float16)v;
    return (f16x2){h, h};
}

// Single kernel. Block = 16-row o-tile, 256 threads (4 waves).
// Weights: global_load_lds staging, 16KB slab (16 rows x 1KB), 2 buffers,
// counted-vmcnt pipeline: s_waitcnt vmcnt(4) + raw s_barrier (stage(s+1)'s
// 4 per-wave loads stay in flight across the barrier; never drain to 0).
// x: fp32 loads (L2-hot) converted to f16 per use — no separate prep kernel.
__global__ __launch_bounds__(256, 4)
void qlin_kernel(const int* __restrict__ wq,
                 const float* __restrict__ scales,
                 const float* __restrict__ zeros,
                 const float* __restrict__ bias,
                 const float* __restrict__ xf,
                 float* __restrict__ out)
{
    __shared__ unsigned char wlds[2][16][1024];   // 32 KB
    __shared__ f32x4 red[4][64];

    const int tid  = threadIdx.x;
    const int wv   = tid >> 6;       // 0..3
    const int lane = tid & 63;
    const int col  = lane & 15;      // B col n = weight row; A row m
    const int kg   = lane >> 4;      // k sub-chunk
    const int o0   = blockIdx.x * 16;
    const int orow = o0 + col;
    const bool mvalid = (col < 8);

    // wave wv's 8 quant groups: g = s*4 + wv  (slab s covers groups 4s..4s+3)
    f16x2 sp[8], zp[8];
    #pragma unroll
    for (int s = 0; s < 8; ++s) {
        sp[s] = bcast(scales[(size_t)orow * NGRP + s * 4 + wv]);
        zp[s] = bcast(zeros [(size_t)orow * NGRP + s * 4 + wv]);
    }

    const char* wtile = (const char*)wq + (size_t)o0 * 8192;   // 8192 B per row

    // stage slab sl into buffer bufi: wave wv stages rows 4wv..4wv+3,
    // one contiguous 1KB row per instruction, source XOR-pre-swizzled.
    auto stage = [&](int sl, int bufi) {
        #pragma unroll
        for (int c = 0; c < 4; ++c) {
            const int r = 4 * wv + c;
            const char* src = wtile + (size_t)r * 8192 + sl * 1024
                              + ((lane * 16) ^ ((r & 7) << 4));
            __builtin_amdgcn_global_load_lds(
                (const __attribute__((address_space(1))) void*)src,
                (__attribute__((address_space(3))) void*)&wlds[bufi][r][0],
                16, 0, 0);
        }
    };

    stage(0, 0);
    stage(1, 1);

    const float* xfcol = xf + (size_t)col * IN_F;
    const unsigned swz = (unsigned)((col & 7) << 4);

    f32x4 acc = {0.f, 0.f, 0.f, 0.f};

    #pragma unroll
    for (int s = 0; s < 8; ++s) {
        // stage(s) must be complete; stage(s+1)'s 4 per-wave loads may fly.
        if (s < 7) asm volatile("s_waitcnt vmcnt(4)" ::: "memory");
        else       asm volatile("s_waitcnt vmcnt(0)" ::: "memory");
        __builtin_amdgcn_s_barrier();
        asm volatile("" ::: "memory");

        const f16x2 s2 = sp[s], z2 = zp[s];
        #pragma unroll
        for (int t = 0; t < 4; ++t) {
            const int k = s * 512 + wv * 128 + t * 32 + kg * 8;
            f16x8 af = (f16x8){0,0,0,0,0,0,0,0};
            if (mvalid) {
                float4 a0 = *(const float4*)(xfcol + k);
                float4 a1 = *(const float4*)(xfcol + k + 4);
                af = (f16x8){(f16)a0.x,(f16)a0.y,(f16)a0.z,(f16)a0.w,
                             (f16)a1.x,(f16)a1.y,(f16)a1.z,(f16)a1.w};
            }
            const unsigned off = ((unsigned)(wv * 256 + t * 64 + kg * 16)) ^ swz;
            const int4 q = *(const int4*)&wlds[s & 1][col][off];
            u32x4 bw = {dq2((unsigned)q.x, s2, z2),
                        dq2((unsigned)q.y, s2, z2),
                        dq2((unsigned)q.z, s2, z2),
                        dq2((unsigned)q.w, s2, z2)};
            f16x8 bfr = __builtin_bit_cast(f16x8, bw);
            acc = __builtin_amdgcn_mfma_f32_16x16x32_f16(af, bfr, acc, 0, 0, 0);
        }

        asm volatile("" ::: "memory");
        __builtin_amdgcn_s_barrier();          // all waves done reading buf s&1
        if (s < 6) stage(s + 2, s & 1);        // refill it
    }

    red[wv][lane] = acc;
    __syncthreads();

    if (tid < 64) {
        f32x4 ssum = red[0][tid];
        #pragma unroll
        for (int w = 1; w < 4; ++w) ssum += red[w][tid];
        const int n = tid & 15;
        const float bb = bias[o0 + n];
        const int mbase = (tid >> 4) * 4;   // C/D row = (lane>>4)*4 + reg
        if (mbase < 8) {
            #pragma unroll
            for (int i = 0; i < 4; ++i)
                out[(size_t)(mbase + i) * OUT_F + o0 + n] = ssum[i] + bb;
        }
    }
}

extern "C" void kernel_launch(void* const* d_in, const int* in_sizes, int n_in,
                              void* d_out, int out_size, void* d_ws, size_t ws_size,
                              hipStream_t stream) {
    const float* x  = (const float*)d_in[0];
    const int*   wq = (const int*)d_in[1];
    const float* sc = (const float*)d_in[2];
    const float* zr = (const float*)d_in[3];
    const float* bs = (const float*)d_in[4];
    float* out = (float*)d_out;
    (void)d_ws; (void)ws_size; (void)in_sizes; (void)n_in;

    qlin_kernel<<<OUT_F / 16, 256, 0, stream>>>(wq, sc, zr, bs, x, out);
}